// Round 6
// baseline (817.668 us; speedup 1.0000x reference)
//
#include <hip/hip_runtime.h>

#define KSL 8
#define DIN 128
#define DOUT 128

typedef __attribute__((ext_vector_type(8))) short bf16x8;
typedef __attribute__((ext_vector_type(4))) float f32x4;

// round-to-nearest-even fp32 -> bf16 bits
static __device__ __forceinline__ unsigned int f2b_bits(float f) {
    unsigned int u = __float_as_uint(f);
    return (u + 0x7fffu + ((u >> 16) & 1u)) >> 16;
}

// ---------------- prep: x->bf16, deg count, W->bf16 [c][k] ----------------
__global__ __launch_bounds__(256) void prep(
        const float* __restrict__ x, uint4* __restrict__ xh, int n8,
        const int* __restrict__ dst, int E, int* __restrict__ deg,
        const float* __restrict__ W, unsigned short* __restrict__ Wh) {
    int tid = blockIdx.x * blockDim.x + threadIdx.x;
    int stride = gridDim.x * blockDim.x;

    for (int i = tid; i < n8; i += stride) {
        const float4* p = (const float4*)x + (size_t)i * 2;
        float4 a = p[0], b = p[1];
        uint4 o;
        o.x = f2b_bits(a.x) | (f2b_bits(a.y) << 16);
        o.y = f2b_bits(a.z) | (f2b_bits(a.w) << 16);
        o.z = f2b_bits(b.x) | (f2b_bits(b.y) << 16);
        o.w = f2b_bits(b.z) | (f2b_bits(b.w) << 16);
        xh[i] = o;
    }
    for (int e = tid; e < E; e += stride) atomicAdd(&deg[dst[e]], 1);

    // W^T as bf16: Wh[c*128 + k], 2048 uint4 chunks of 8 k's
    for (int i = tid; i < 2048; i += stride) {
        int c = i >> 4;
        int k0 = (i & 15) * 8;
        uint4 o;
        o.x = f2b_bits(W[(size_t)(k0 + 0) * 128 + c]) |
             (f2b_bits(W[(size_t)(k0 + 1) * 128 + c]) << 16);
        o.y = f2b_bits(W[(size_t)(k0 + 2) * 128 + c]) |
             (f2b_bits(W[(size_t)(k0 + 3) * 128 + c]) << 16);
        o.z = f2b_bits(W[(size_t)(k0 + 4) * 128 + c]) |
             (f2b_bits(W[(size_t)(k0 + 5) * 128 + c]) << 16);
        o.w = f2b_bits(W[(size_t)(k0 + 6) * 128 + c]) |
             (f2b_bits(W[(size_t)(k0 + 7) * 128 + c]) << 16);
        *(uint4*)(Wh + (size_t)c * 128 + k0) = o;
    }
}

// ---------------- CSR offsets: serial chunks + one block scan ----------------
__global__ __launch_bounds__(1024) void scan_off_fast(const int* __restrict__ deg, int N,
                                                      int* __restrict__ off,
                                                      float* __restrict__ dinv) {
    __shared__ int part[1024];
    int tid = threadIdx.x;
    int CH = (N + 1023) / 1024;
    int i0 = tid * CH;
    int s = 0;
    for (int j = 0; j < CH; j++) {
        int i = i0 + j;
        if (i < N) {
            int d = deg[i];
            dinv[i] = rsqrtf((float)(d + 1));   // +1 self-loop
            s += d;
        }
    }
    part[tid] = s;
    __syncthreads();
    for (int st = 1; st < 1024; st <<= 1) {
        int t = (tid >= st) ? part[tid - st] : 0;
        __syncthreads();
        part[tid] += t;
        __syncthreads();
    }
    int run = part[tid] - s;   // exclusive prefix
    for (int j = 0; j < CH; j++) {
        int i = i0 + j;
        if (i < N) {
            off[i] = run;
            run += deg[i];
        }
    }
    if (tid == 1023) off[N] = part[1023];
}

__global__ void fill_csr(const int* __restrict__ src, const int* __restrict__ dst, int E,
                         const int* __restrict__ off, int* __restrict__ cursor,
                         const float* __restrict__ dinv,
                         int2* __restrict__ csr) {
    int e = blockIdx.x * blockDim.x + threadIdx.x;
    if (e < E) {
        int s = src[e], d = dst[e];
        int pos = atomicAdd(&cursor[d], 1);
        csr[off[d] + pos] = make_int2(s, __float_as_int(dinv[s] * dinv[d]));
    }
}

// ---------------- fused aggregate + MFMA GEMM + bias + ReLU ----------------
// One wave per node-pair (16 rows of [N*K, 128]). Gather layout == MFMA
// fragment layout: lane l owns row (l&15), elements d = kt*32 + (l>>4)*8 + e.
// j-loop unrolled 2x with csr prefetch (8 gather + 2 csr loads in flight).
// SWAPPED-OPERAND epilogue: acct = mfma(W_frag, X_frag); D transposed ->
// lane stores float4 of 4 consecutive cols; NT stores bypass L3 so xh stays
// L3-resident (round-5 counters: out-stream evicted xh, 9x HBM re-fetch).
__global__ __launch_bounds__(256, 6) void aggemm(
        const char* __restrict__ xb,
        const int* __restrict__ off,
        const int2* __restrict__ csr,
        const float* __restrict__ dinv,
        const unsigned short* __restrict__ Wh, const float* __restrict__ bias,
        int N, float* __restrict__ out) {
    int t = threadIdx.x;
    int wid = t >> 6, lane = t & 63;
    int pair = blockIdx.x * 4 + wid;
    int n0 = pair * 2;
    if (n0 >= N) return;

    int rit = lane & 15;          // row in 16-row tile
    int g   = lane >> 4;          // k-group 0..3
    int mynode = n0 + (rit >> 3);
    bool rowok = (mynode < N);    // odd-N guard
    if (!rowok) mynode = n0;
    int kslice = rit & 7;

    int offA = off[n0];
    int offMid = off[n0 + 1];
    int offEnd = (n0 + 2 <= N) ? off[n0 + 2] : offMid;
    int degA = offMid - offA;
    int degB = (n0 + 1 < N) ? (offEnd - offMid) : 0;
    int maxd = max(degA, degB);
    int myoff = (rit < 8) ? offA : offMid;
    int mydeg = (rit < 8) ? degA : degB;
    int dm1 = (mydeg > 0) ? (mydeg - 1) : 0;

    const size_t lofs = (size_t)(kslice * 256 + g * 16);
    float acc[32];

    // self-loop init: acc = x[mynode] * dinv^2
    {
        float dself = dinv[mynode];
        float ns = dself * dself;
        const char* rb = xb + (size_t)mynode * 2048 + lofs;
        #pragma unroll
        for (int kt = 0; kt < 4; kt++) {
            uint4 q = *(const uint4*)(rb + kt * 64);
            acc[kt * 8 + 0] = __uint_as_float(q.x << 16) * ns;
            acc[kt * 8 + 1] = __uint_as_float(q.x & 0xffff0000u) * ns;
            acc[kt * 8 + 2] = __uint_as_float(q.y << 16) * ns;
            acc[kt * 8 + 3] = __uint_as_float(q.y & 0xffff0000u) * ns;
            acc[kt * 8 + 4] = __uint_as_float(q.z << 16) * ns;
            acc[kt * 8 + 5] = __uint_as_float(q.z & 0xffff0000u) * ns;
            acc[kt * 8 + 6] = __uint_as_float(q.w << 16) * ns;
            acc[kt * 8 + 7] = __uint_as_float(q.w & 0xffff0000u) * ns;
        }
    }

    // edge loop, unrolled by 2 with csr prefetch
    int2 c0 = csr[myoff + 0];               // safe: csr has E+1 entries
    int2 c1 = csr[myoff + min(1, dm1)];
    for (int j = 0; j < maxd; j += 2) {
        int   s0 = (j     < mydeg) ? c0.x : mynode;
        float w0 = (j     < mydeg) ? __int_as_float(c0.y) : 0.f;
        int   s1 = (j + 1 < mydeg) ? c1.x : mynode;
        float w1 = (j + 1 < mydeg) ? __int_as_float(c1.y) : 0.f;

        const char* r0 = xb + (size_t)s0 * 2048 + lofs;
        const char* r1 = xb + (size_t)s1 * 2048 + lofs;
        uint4 q0[4], q1[4];
        #pragma unroll
        for (int kt = 0; kt < 4; kt++) q0[kt] = *(const uint4*)(r0 + kt * 64);
        #pragma unroll
        for (int kt = 0; kt < 4; kt++) q1[kt] = *(const uint4*)(r1 + kt * 64);

        // prefetch next pair's csr entries (clamped in-bounds)
        c0 = csr[myoff + min(j + 2, dm1)];
        c1 = csr[myoff + min(j + 3, dm1)];

        #pragma unroll
        for (int kt = 0; kt < 4; kt++) {
            uint4 q = q0[kt];
            acc[kt * 8 + 0] += __uint_as_float(q.x << 16) * w0;
            acc[kt * 8 + 1] += __uint_as_float(q.x & 0xffff0000u) * w0;
            acc[kt * 8 + 2] += __uint_as_float(q.y << 16) * w0;
            acc[kt * 8 + 3] += __uint_as_float(q.y & 0xffff0000u) * w0;
            acc[kt * 8 + 4] += __uint_as_float(q.z << 16) * w0;
            acc[kt * 8 + 5] += __uint_as_float(q.z & 0xffff0000u) * w0;
            acc[kt * 8 + 6] += __uint_as_float(q.w << 16) * w0;
            acc[kt * 8 + 7] += __uint_as_float(q.w & 0xffff0000u) * w0;
        }
        #pragma unroll
        for (int kt = 0; kt < 4; kt++) {
            uint4 q = q1[kt];
            acc[kt * 8 + 0] += __uint_as_float(q.x << 16) * w1;
            acc[kt * 8 + 1] += __uint_as_float(q.x & 0xffff0000u) * w1;
            acc[kt * 8 + 2] += __uint_as_float(q.y << 16) * w1;
            acc[kt * 8 + 3] += __uint_as_float(q.y & 0xffff0000u) * w1;
            acc[kt * 8 + 4] += __uint_as_float(q.z << 16) * w1;
            acc[kt * 8 + 5] += __uint_as_float(q.z & 0xffff0000u) * w1;
            acc[kt * 8 + 6] += __uint_as_float(q.w << 16) * w1;
            acc[kt * 8 + 7] += __uint_as_float(q.w & 0xffff0000u) * w1;
        }
    }

    // pack accumulators -> bf16 fragments (same regs valid as A or B operand)
    bf16x8 xfrag[4];
    #pragma unroll
    for (int kt = 0; kt < 4; kt++) {
        #pragma unroll
        for (int e = 0; e < 8; e++)
            xfrag[kt][e] = (short)f2b_bits(acc[kt * 8 + e]);
    }

    // Swapped GEMM: D = (W^T_tile) x (Xagg^T); lane l -> out[row][c0+g*4..+3]
    long long row = (long long)n0 * 8 + rit;
    #pragma unroll
    for (int ct = 0; ct < 8; ct++) {
        int cb = ct * 16;
        f32x4 acct = {0.f, 0.f, 0.f, 0.f};
        #pragma unroll
        for (int kt = 0; kt < 4; kt++) {
            bf16x8 wfrag = *(const bf16x8*)(Wh + (size_t)(cb + rit) * 128 + kt * 32 + g * 8);
            acct = __builtin_amdgcn_mfma_f32_16x16x32_bf16(wfrag, xfrag[kt], acct, 0, 0, 0);
        }
        if (rowok) {
            f32x4 bv = *(const f32x4*)(bias + cb + g * 4);
            f32x4 o;
            o[0] = fmaxf(acct[0] + bv[0], 0.f);
            o[1] = fmaxf(acct[1] + bv[1], 0.f);
            o[2] = fmaxf(acct[2] + bv[2], 0.f);
            o[3] = fmaxf(acct[3] + bv[3], 0.f);
            __builtin_nontemporal_store(o, (f32x4*)(out + row * 128 + cb + g * 4));
        }
    }
}

// ---------------- launch ----------------
extern "C" void kernel_launch(void* const* d_in, const int* in_sizes, int n_in,
                              void* d_out, int out_size, void* d_ws, size_t ws_size,
                              hipStream_t stream) {
    const float* x  = (const float*)d_in[0];
    const int*   ei = (const int*)d_in[1];
    const float* W  = (const float*)d_in[2];
    const float* b  = (const float*)d_in[3];
    float* out = (float*)d_out;

    int N = in_sizes[0] / (KSL * DIN);
    int E = in_sizes[1] / 2;
    const int* src = ei;
    const int* dst = ei + E;

    char* ws = (char*)d_ws;
    size_t o = 0;
    auto alloc = [&](size_t bytes) -> void* {
        o = (o + 255) & ~(size_t)255;
        void* p = ws + o;
        o += bytes;
        return p;
    };
    int*   deg    = (int*)alloc((size_t)N * 4);
    int*   off    = (int*)alloc((size_t)(N + 1) * 4);
    int*   cursor = (int*)alloc((size_t)N * 4);
    float* dinv   = (float*)alloc((size_t)N * 4);
    int2*  csr    = (int2*)alloc((size_t)(E + 1) * 8);
    unsigned short* Wh = (unsigned short*)alloc((size_t)DIN * DOUT * 2);
    uint4* xh     = (uint4*)alloc((size_t)N * KSL * DIN * 2);

    hipMemsetAsync(deg, 0, (size_t)N * 4, stream);
    hipMemsetAsync(cursor, 0, (size_t)N * 4, stream);

    int n8 = N * KSL * DIN / 8;
    prep<<<2048, 256, 0, stream>>>(x, xh, n8, dst, E, deg, W, Wh);
    scan_off_fast<<<1, 1024, 0, stream>>>(deg, N, off, dinv);
    fill_csr<<<(E + 255) / 256, 256, 0, stream>>>(src, dst, E, off, cursor, dinv, csr);

    int pairs = (N + 1) / 2;
    int blocks = (pairs + 3) / 4;
    aggemm<<<blocks, 256, 0, stream>>>((const char*)xh, off, csr, dinv,
                                       Wh, b, N, out);
}

// Round 7
// 610.957 us; speedup vs baseline: 1.3383x; 1.3383x over previous
//
#include <hip/hip_runtime.h>

#define KSL 8
#define DIN 128
#define DOUT 128

typedef __attribute__((ext_vector_type(8))) short bf16x8;
typedef __attribute__((ext_vector_type(4))) float f32x4;

// round-to-nearest-even fp32 -> bf16 bits
static __device__ __forceinline__ unsigned int f2b_bits(float f) {
    unsigned int u = __float_as_uint(f);
    return (u + 0x7fffu + ((u >> 16) & 1u)) >> 16;
}

// ---------------- prep: x->bf16, deg count ----------------
__global__ __launch_bounds__(256) void prep(
        const float* __restrict__ x, uint4* __restrict__ xh, int n8,
        const int* __restrict__ dst, int E, int* __restrict__ deg) {
    int tid = blockIdx.x * blockDim.x + threadIdx.x;
    int stride = gridDim.x * blockDim.x;

    for (int i = tid; i < n8; i += stride) {
        const float4* p = (const float4*)x + (size_t)i * 2;
        float4 a = p[0], b = p[1];
        uint4 o;
        o.x = f2b_bits(a.x) | (f2b_bits(a.y) << 16);
        o.y = f2b_bits(a.z) | (f2b_bits(a.w) << 16);
        o.z = f2b_bits(b.x) | (f2b_bits(b.y) << 16);
        o.w = f2b_bits(b.z) | (f2b_bits(b.w) << 16);
        xh[i] = o;
    }
    for (int e = tid; e < E; e += stride) atomicAdd(&deg[dst[e]], 1);
}

// ---------------- CSR offsets: serial chunks + one block scan ----------------
__global__ __launch_bounds__(1024) void scan_off_fast(const int* __restrict__ deg, int N,
                                                      int* __restrict__ off,
                                                      float* __restrict__ dinv) {
    __shared__ int part[1024];
    int tid = threadIdx.x;
    int CH = (N + 1023) / 1024;
    int i0 = tid * CH;
    int s = 0;
    for (int j = 0; j < CH; j++) {
        int i = i0 + j;
        if (i < N) {
            int d = deg[i];
            dinv[i] = rsqrtf((float)(d + 1));   // +1 self-loop
            s += d;
        }
    }
    part[tid] = s;
    __syncthreads();
    for (int st = 1; st < 1024; st <<= 1) {
        int t = (tid >= st) ? part[tid - st] : 0;
        __syncthreads();
        part[tid] += t;
        __syncthreads();
    }
    int run = part[tid] - s;   // exclusive prefix
    for (int j = 0; j < CH; j++) {
        int i = i0 + j;
        if (i < N) {
            off[i] = run;
            run += deg[i];
        }
    }
    if (tid == 1023) off[N] = part[1023];
}

__global__ void fill_csr(const int* __restrict__ src, const int* __restrict__ dst, int E,
                         const int* __restrict__ off, int* __restrict__ cursor,
                         const float* __restrict__ dinv,
                         int2* __restrict__ csr) {
    int e = blockIdx.x * blockDim.x + threadIdx.x;
    if (e < E) {
        int s = src[e], d = dst[e];
        int pos = atomicAdd(&cursor[d], 1);
        csr[off[d] + pos] = make_int2(s, __float_as_int(dinv[s] * dinv[d]));
    }
}

// ---------------- fused aggregate + MFMA GEMM + bias + ReLU ----------------
// K-SPLIT (pass PASS of 2): a wave owns a QUAD of nodes x 4 k-slices = 16 rows
// of [N*K, 128]. Per-pass live set = xh-half(51MB) + out-half(102MB) + csr(7MB)
// = 160MB < 256MB L3 -> gather is L3-resident (round-5/6 counters showed
// 9x HBM re-fetch when the full 314MB set thrashed L3). Passes MUST be
// sequential dispatches: temporal separation is the mechanism.
// Gather layout == MFMA A-frag layout: lane l owns tile-row (l&15) ->
// (node = n0+(rit>>2), kslice = (rit&3)+PASS*4), elems d = kt*32+(l>>4)*8+e.
// Epilogue/stores: round-2 exact (LDS W^T swizzled, scalar plain stores,
// WRITE_SIZE was a perfect 200MB).
template <int PASS>
__global__ __launch_bounds__(256) void aggemm(
        const char* __restrict__ xb,
        const int* __restrict__ off,
        const int2* __restrict__ csr,
        const float* __restrict__ dinv,
        const float* __restrict__ W, const float* __restrict__ bias,
        int N, float* __restrict__ out) {
    __shared__ unsigned short Wt[128 * 128];   // [c][k] bf16, XOR-swizzled, 32 KB

    int t = threadIdx.x;
    // ---- stage W^T as bf16 with XOR swizzle on byte bits 4..6 (r2-verified) ----
    {
        int c = t & 127;
        int khalf = t >> 7;
        #pragma unroll
        for (int kc = 0; kc < 8; kc++) {
            int k0 = khalf * 64 + kc * 8;
            unsigned int u0 = f2b_bits(W[(size_t)(k0 + 0) * 128 + c]) |
                             (f2b_bits(W[(size_t)(k0 + 1) * 128 + c]) << 16);
            unsigned int u1 = f2b_bits(W[(size_t)(k0 + 2) * 128 + c]) |
                             (f2b_bits(W[(size_t)(k0 + 3) * 128 + c]) << 16);
            unsigned int u2 = f2b_bits(W[(size_t)(k0 + 4) * 128 + c]) |
                             (f2b_bits(W[(size_t)(k0 + 5) * 128 + c]) << 16);
            unsigned int u3 = f2b_bits(W[(size_t)(k0 + 6) * 128 + c]) |
                             (f2b_bits(W[(size_t)(k0 + 7) * 128 + c]) << 16);
            int byte = c * 256 + k0 * 2;
            byte ^= (c & 7) << 4;
            *(uint4*)((char*)Wt + byte) = make_uint4(u0, u1, u2, u3);
        }
    }
    __syncthreads();

    int wid = t >> 6, lane = t & 63;
    int quad = blockIdx.x * 4 + wid;
    int n0 = quad * 4;
    if (n0 >= N) return;

    int rit = lane & 15;              // tile row
    int g   = lane >> 4;              // k-group 0..3
    int nid = rit >> 2;               // node within quad 0..3
    int node = n0 + nid;
    if (node >= N) node = n0;         // tail guard (N%4==0 in practice)
    int kslice = (rit & 3) + PASS * 4;

    // per-quad edge-list bounds (n0 uniform per wave -> scalar loads)
    int o0 = off[n0];
    int o1 = off[min(n0 + 1, N)];
    int o2 = off[min(n0 + 2, N)];
    int o3 = off[min(n0 + 3, N)];
    int o4 = off[min(n0 + 4, N)];
    int d0 = o1 - o0, d1 = o2 - o1, d2 = o3 - o2, d3 = o4 - o3;
    int maxd = max(max(d0, d1), max(d2, d3));
    int myoff = (nid == 0) ? o0 : (nid == 1) ? o1 : (nid == 2) ? o2 : o3;
    int mydeg = (nid == 0) ? d0 : (nid == 1) ? d1 : (nid == 2) ? d2 : d3;

    const size_t lofs = (size_t)(kslice * 256 + g * 16);

    float acc[32];
    // self-loop init: acc = x[node] * dinv^2
    {
        float ds = dinv[node];
        float ns = ds * ds;
        const char* rb = xb + (size_t)node * 2048 + lofs;
        #pragma unroll
        for (int kt = 0; kt < 4; kt++) {
            uint4 q = *(const uint4*)(rb + kt * 64);
            acc[kt * 8 + 0] = __uint_as_float(q.x << 16) * ns;
            acc[kt * 8 + 1] = __uint_as_float(q.x & 0xffff0000u) * ns;
            acc[kt * 8 + 2] = __uint_as_float(q.y << 16) * ns;
            acc[kt * 8 + 3] = __uint_as_float(q.y & 0xffff0000u) * ns;
            acc[kt * 8 + 4] = __uint_as_float(q.z << 16) * ns;
            acc[kt * 8 + 5] = __uint_as_float(q.z & 0xffff0000u) * ns;
            acc[kt * 8 + 6] = __uint_as_float(q.w << 16) * ns;
            acc[kt * 8 + 7] = __uint_as_float(q.w & 0xffff0000u) * ns;
        }
    }

    for (int j = 0; j < maxd; j++) {
        int s;
        float nrm;
        if (j < mydeg) {
            int2 cc = csr[myoff + j];
            s = cc.x;
            nrm = __int_as_float(cc.y);
        } else {
            s = node;
            nrm = 0.f;
        }
        const char* rb = xb + (size_t)s * 2048 + lofs;
        #pragma unroll
        for (int kt = 0; kt < 4; kt++) {
            uint4 q = *(const uint4*)(rb + kt * 64);
            acc[kt * 8 + 0] += __uint_as_float(q.x << 16) * nrm;
            acc[kt * 8 + 1] += __uint_as_float(q.x & 0xffff0000u) * nrm;
            acc[kt * 8 + 2] += __uint_as_float(q.y << 16) * nrm;
            acc[kt * 8 + 3] += __uint_as_float(q.y & 0xffff0000u) * nrm;
            acc[kt * 8 + 4] += __uint_as_float(q.z << 16) * nrm;
            acc[kt * 8 + 5] += __uint_as_float(q.z & 0xffff0000u) * nrm;
            acc[kt * 8 + 6] += __uint_as_float(q.w << 16) * nrm;
            acc[kt * 8 + 7] += __uint_as_float(q.w & 0xffff0000u) * nrm;
        }
    }

    // pack accumulators -> A fragments (bf16)
    bf16x8 afrag[4];
    #pragma unroll
    for (int kt = 0; kt < 4; kt++) {
        #pragma unroll
        for (int e = 0; e < 8; e++)
            afrag[kt][e] = (short)f2b_bits(acc[kt * 8 + e]);
    }

    // GEMM: 8 column tiles of 16, K = 128 in 4 MFMAs each; B-frags from LDS.
    // D: col = lane&15 (=rit -> output col c), row m = g*4 + r -> tile row ->
    // out_row = (n0 + (m>>2))*8 + (m&3) + PASS*4.
    #pragma unroll
    for (int ct = 0; ct < 8; ct++) {
        int c = ct * 16 + rit;
        f32x4 acct = {0.f, 0.f, 0.f, 0.f};
        #pragma unroll
        for (int kt = 0; kt < 4; kt++) {
            int byte = c * 256 + kt * 64 + g * 16;
            byte ^= (c & 7) << 4;
            bf16x8 bfrag = *(const bf16x8*)((const char*)Wt + byte);
            acct = __builtin_amdgcn_mfma_f32_16x16x32_bf16(afrag[kt], bfrag, acct, 0, 0, 0);
        }
        float bv = bias[c];
        #pragma unroll
        for (int r = 0; r < 4; r++) {
            int m = g * 4 + r;
            int nm = n0 + (m >> 2);
            if (nm < N) {
                size_t row = (size_t)nm * 8 + (m & 3) + PASS * 4;
                out[row * 128 + c] = fmaxf(acct[r] + bv, 0.f);
            }
        }
    }
}

// ---------------- launch ----------------
extern "C" void kernel_launch(void* const* d_in, const int* in_sizes, int n_in,
                              void* d_out, int out_size, void* d_ws, size_t ws_size,
                              hipStream_t stream) {
    const float* x  = (const float*)d_in[0];
    const int*   ei = (const int*)d_in[1];
    const float* W  = (const float*)d_in[2];
    const float* b  = (const float*)d_in[3];
    float* out = (float*)d_out;

    int N = in_sizes[0] / (KSL * DIN);
    int E = in_sizes[1] / 2;
    const int* src = ei;
    const int* dst = ei + E;

    char* ws = (char*)d_ws;
    size_t o = 0;
    auto alloc = [&](size_t bytes) -> void* {
        o = (o + 255) & ~(size_t)255;
        void* p = ws + o;
        o += bytes;
        return p;
    };
    int*   deg    = (int*)alloc((size_t)N * 4);
    int*   off    = (int*)alloc((size_t)(N + 1) * 4);
    int*   cursor = (int*)alloc((size_t)N * 4);
    float* dinv   = (float*)alloc((size_t)N * 4);
    int2*  csr    = (int2*)alloc((size_t)(E + 1) * 8);
    uint4* xh     = (uint4*)alloc((size_t)N * KSL * DIN * 2);

    hipMemsetAsync(deg, 0, (size_t)N * 4, stream);
    hipMemsetAsync(cursor, 0, (size_t)N * 4, stream);

    int n8 = N * KSL * DIN / 8;
    prep<<<2048, 256, 0, stream>>>(x, xh, n8, dst, E, deg);
    scan_off_fast<<<1, 1024, 0, stream>>>(deg, N, off, dinv);
    fill_csr<<<(E + 255) / 256, 256, 0, stream>>>(src, dst, E, off, cursor, dinv, csr);

    int quads = (N + 3) / 4;
    int blocks = (quads + 3) / 4;
    // Sequential passes: each pass's gather working set fits L3.
    aggemm<0><<<blocks, 256, 0, stream>>>((const char*)xh, off, csr, dinv,
                                          W, b, N, out);
    aggemm<1><<<blocks, 256, 0, stream>>>((const char*)xh, off, csr, dinv,
                                          W, b, N, out);
}

// Round 8
// 571.897 us; speedup vs baseline: 1.4297x; 1.0683x over previous
//
#include <hip/hip_runtime.h>

#define KSL 8
#define DIN 128
#define DOUT 128

typedef __attribute__((ext_vector_type(8))) short bf16x8;
typedef __attribute__((ext_vector_type(8))) signed char char8;
typedef __attribute__((ext_vector_type(4))) float f32x4;

// round-to-nearest-even fp32 -> bf16 bits
static __device__ __forceinline__ unsigned int f2b_bits(float f) {
    unsigned int u = __float_as_uint(f);
    return (u + 0x7fffu + ((u >> 16) & 1u)) >> 16;
}

// ---------------- x -> int8 rows, per-(node,k) amax scale ----------------
// One wave per 128-elem row: lane reads 2 floats, wave-allreduce amax,
// quantize q = rn(x*127/amax), store 2 bytes/lane; scale = amax/127.
__global__ __launch_bounds__(256) void quant_rows(
        const float* __restrict__ x, char* __restrict__ xq,
        float* __restrict__ scales, int nrows) {
    int w = (int)((blockIdx.x * (unsigned)blockDim.x + threadIdx.x) >> 6);
    int lane = threadIdx.x & 63;
    if (w >= nrows) return;
    float2 v = *(const float2*)(x + (size_t)w * 128 + lane * 2);
    float m = fmaxf(fabsf(v.x), fabsf(v.y));
    #pragma unroll
    for (int s = 32; s > 0; s >>= 1) m = fmaxf(m, __shfl_xor(m, s));
    float inv = (m > 0.f) ? 127.f / m : 0.f;
    int qa = __float2int_rn(v.x * inv);
    int qb = __float2int_rn(v.y * inv);
    unsigned short pk = (unsigned short)((qa & 0xff) | ((qb & 0xff) << 8));
    *(unsigned short*)(xq + (size_t)w * 128 + lane * 2) = pk;
    if (lane == 0) scales[w] = m * (1.f / 127.f);
}

// ---------------- deg count: int4 edge loads ----------------
__global__ __launch_bounds__(256) void count_deg(const int* __restrict__ dst, int E,
                                                 int* __restrict__ deg) {
    int i = blockIdx.x * blockDim.x + threadIdx.x;
    int e4 = E >> 2;
    if (i < e4) {
        int4 d = ((const int4*)dst)[i];
        atomicAdd(&deg[d.x], 1);
        atomicAdd(&deg[d.y], 1);
        atomicAdd(&deg[d.z], 1);
        atomicAdd(&deg[d.w], 1);
    }
    if (i < (E & 3)) atomicAdd(&deg[dst[e4 * 4 + i]], 1);
}

// ---------------- CSR offsets: serial chunks + one block scan ----------------
__global__ __launch_bounds__(1024) void scan_off_fast(const int* __restrict__ deg, int N,
                                                      int* __restrict__ off,
                                                      float* __restrict__ dinv) {
    __shared__ int part[1024];
    int tid = threadIdx.x;
    int CH = (N + 1023) / 1024;
    int i0 = tid * CH;
    int s = 0;
    for (int j = 0; j < CH; j++) {
        int i = i0 + j;
        if (i < N) {
            int d = deg[i];
            dinv[i] = rsqrtf((float)(d + 1));   // +1 self-loop
            s += d;
        }
    }
    part[tid] = s;
    __syncthreads();
    for (int st = 1; st < 1024; st <<= 1) {
        int t = (tid >= st) ? part[tid - st] : 0;
        __syncthreads();
        part[tid] += t;
        __syncthreads();
    }
    int run = part[tid] - s;   // exclusive prefix
    for (int j = 0; j < CH; j++) {
        int i = i0 + j;
        if (i < N) {
            off[i] = run;
            run += deg[i];
        }
    }
    if (tid == 1023) off[N] = part[1023];
}

// ---------------- CSR fill: int4 edge loads ----------------
__global__ __launch_bounds__(256) void fill_csr(
        const int* __restrict__ src, const int* __restrict__ dst, int E,
        const int* __restrict__ off, int* __restrict__ cursor,
        const float* __restrict__ dinv, int2* __restrict__ csr) {
    int i = blockIdx.x * blockDim.x + threadIdx.x;
    int e4 = E >> 2;
    if (i < e4) {
        int4 s4 = ((const int4*)src)[i];
        int4 d4 = ((const int4*)dst)[i];
        int pos;
        pos = atomicAdd(&cursor[d4.x], 1);
        csr[off[d4.x] + pos] = make_int2(s4.x, __float_as_int(dinv[s4.x] * dinv[d4.x]));
        pos = atomicAdd(&cursor[d4.y], 1);
        csr[off[d4.y] + pos] = make_int2(s4.y, __float_as_int(dinv[s4.y] * dinv[d4.y]));
        pos = atomicAdd(&cursor[d4.z], 1);
        csr[off[d4.z] + pos] = make_int2(s4.z, __float_as_int(dinv[s4.z] * dinv[d4.z]));
        pos = atomicAdd(&cursor[d4.w], 1);
        csr[off[d4.w] + pos] = make_int2(s4.w, __float_as_int(dinv[s4.w] * dinv[d4.w]));
    }
    if (i < (E & 3)) {
        int e = e4 * 4 + i;
        int s = src[e], d = dst[e];
        int pos = atomicAdd(&cursor[d], 1);
        csr[off[d] + pos] = make_int2(s, __float_as_int(dinv[s] * dinv[d]));
    }
}

// ---------------- fused aggregate + MFMA GEMM + bias + ReLU ----------------
// Round-2 structure EXACTLY (fastest + deterministic-proven), payload int8:
// one wave per node-pair (16 rows of [N*K,128]); gather layout == MFMA A-frag
// layout (lane l: row=l&15, elems d = kt*32 + (l>>4)*8 + e). Per-edge weight
// folds the source row's int8 scale: wgt = norm_e * scales[s*8+kslice].
// W staged bf16 XOR-swizzled in LDS; scalar plain stores (WRITE was an exact
// 200 MB in r2 — NT variants measured 1.5x/4.2x amplification, never again).
__global__ __launch_bounds__(256) void aggemm(
        const char* __restrict__ xq, const float* __restrict__ scales,
        const int* __restrict__ off, const int2* __restrict__ csr,
        const float* __restrict__ dinv,
        const float* __restrict__ W, const float* __restrict__ bias,
        int N, float* __restrict__ out) {
    __shared__ unsigned short Wt[128 * 128];   // [c][k] bf16, XOR-swizzled, 32 KB

    int t = threadIdx.x;
    // ---- stage W^T as bf16 with XOR swizzle on byte bits 4..6 (r2-verified) ----
    {
        int c = t & 127;
        int khalf = t >> 7;
        #pragma unroll
        for (int kc = 0; kc < 8; kc++) {
            int k0 = khalf * 64 + kc * 8;
            unsigned int u0 = f2b_bits(W[(size_t)(k0 + 0) * 128 + c]) |
                             (f2b_bits(W[(size_t)(k0 + 1) * 128 + c]) << 16);
            unsigned int u1 = f2b_bits(W[(size_t)(k0 + 2) * 128 + c]) |
                             (f2b_bits(W[(size_t)(k0 + 3) * 128 + c]) << 16);
            unsigned int u2 = f2b_bits(W[(size_t)(k0 + 4) * 128 + c]) |
                             (f2b_bits(W[(size_t)(k0 + 5) * 128 + c]) << 16);
            unsigned int u3 = f2b_bits(W[(size_t)(k0 + 6) * 128 + c]) |
                             (f2b_bits(W[(size_t)(k0 + 7) * 128 + c]) << 16);
            int byte = c * 256 + k0 * 2;
            byte ^= (c & 7) << 4;
            *(uint4*)((char*)Wt + byte) = make_uint4(u0, u1, u2, u3);
        }
    }
    __syncthreads();

    int wid = t >> 6, lane = t & 63;
    int pair = blockIdx.x * 4 + wid;
    int n0 = pair * 2;
    if (n0 >= N) return;

    int rit = lane & 15;          // row in 16-row tile
    int g   = lane >> 4;          // k-group 0..3
    int mynode = n0 + (rit >> 3);
    if (mynode >= N) mynode = n0; // odd-N guard
    int kslice = rit & 7;

    int offA = off[n0];
    int offMid = off[n0 + 1];
    int offEnd = (n0 + 2 <= N) ? off[n0 + 2] : offMid;
    int degA = offMid - offA;
    int degB = (n0 + 1 < N) ? (offEnd - offMid) : 0;
    int maxd = max(degA, degB);
    int myoff = (rit < 8) ? offA : offMid;
    int mydeg = (rit < 8) ? degA : degB;

    const size_t rofs = (size_t)kslice * 128 + g * 8;   // byte offset in 1KB row

    float acc[32];
    #pragma unroll
    for (int i = 0; i < 32; i++) acc[i] = 0.f;

    float dself = dinv[mynode];
    for (int j = -1; j < maxd; j++) {
        int s;
        float nrm;
        if (j < 0) {
            s = mynode;
            nrm = dself * dself;
        } else if (j < mydeg) {
            int2 cc = csr[myoff + j];
            s = cc.x;
            nrm = __int_as_float(cc.y);
        } else {
            s = mynode;
            nrm = 0.f;
        }
        float wgt = nrm * scales[s * 8 + kslice];
        const char* rb = xq + (size_t)s * 1024 + rofs;
        #pragma unroll
        for (int kt = 0; kt < 4; kt++) {
            char8 q = *(const char8*)(rb + kt * 32);
            #pragma unroll
            for (int e = 0; e < 8; e++)
                acc[kt * 8 + e] += (float)q[e] * wgt;
        }
    }

    // pack accumulators -> A fragments (bf16)
    bf16x8 afrag[4];
    #pragma unroll
    for (int kt = 0; kt < 4; kt++) {
        #pragma unroll
        for (int e = 0; e < 8; e++)
            afrag[kt][e] = (short)f2b_bits(acc[kt * 8 + e]);
    }

    // GEMM: 8 column tiles of 16, K = 128 in 4 MFMAs each; B-frags from LDS
    long long r0 = (long long)n0 * 8;
    #pragma unroll
    for (int ct = 0; ct < 8; ct++) {
        int c = ct * 16 + rit;     // output column (C/D: col = lane&15)
        f32x4 acct = {0.f, 0.f, 0.f, 0.f};
        #pragma unroll
        for (int kt = 0; kt < 4; kt++) {
            int byte = c * 256 + kt * 64 + g * 16;
            byte ^= (c & 7) << 4;
            bf16x8 bfrag = *(const bf16x8*)((const char*)Wt + byte);
            acct = __builtin_amdgcn_mfma_f32_16x16x32_bf16(afrag[kt], bfrag, acct, 0, 0, 0);
        }
        float bv = bias[c];
        #pragma unroll
        for (int r = 0; r < 4; r++) {
            long long row = r0 + g * 4 + r;   // C/D: row = (lane>>4)*4 + reg
            out[row * 128 + c] = fmaxf(acct[r] + bv, 0.f);
        }
    }
}

// ---------------- launch ----------------
extern "C" void kernel_launch(void* const* d_in, const int* in_sizes, int n_in,
                              void* d_out, int out_size, void* d_ws, size_t ws_size,
                              hipStream_t stream) {
    const float* x  = (const float*)d_in[0];
    const int*   ei = (const int*)d_in[1];
    const float* W  = (const float*)d_in[2];
    const float* b  = (const float*)d_in[3];
    float* out = (float*)d_out;

    int N = in_sizes[0] / (KSL * DIN);
    int E = in_sizes[1] / 2;
    const int* src = ei;
    const int* dst = ei + E;

    char* ws = (char*)d_ws;
    size_t o = 0;
    auto alloc = [&](size_t bytes) -> void* {
        o = (o + 255) & ~(size_t)255;
        void* p = ws + o;
        o += bytes;
        return p;
    };
    int*   deg    = (int*)alloc((size_t)N * 4);
    int*   cursor = (int*)alloc((size_t)N * 4);     // adjacent to deg: one memset
    int*   off    = (int*)alloc((size_t)(N + 1) * 4);
    float* dinv   = (float*)alloc((size_t)N * 4);
    int2*  csr    = (int2*)alloc((size_t)(E + 1) * 8);
    float* scales = (float*)alloc((size_t)N * KSL * 4);
    char*  xq     = (char*)alloc((size_t)N * KSL * DIN);

    // one memset covers deg + alignment gap + cursor
    size_t z_bytes = (size_t)((char*)cursor - (char*)deg) + (size_t)N * 4;
    hipMemsetAsync(deg, 0, z_bytes, stream);

    int nrows = N * KSL;
    int qblocks = (nrows * 64 + 255) / 256;
    quant_rows<<<qblocks, 256, 0, stream>>>(x, xq, scales, nrows);
    count_deg<<<((E >> 2) + 255) / 256, 256, 0, stream>>>(dst, E, deg);
    scan_off_fast<<<1, 1024, 0, stream>>>(deg, N, off, dinv);
    fill_csr<<<((E >> 2) + 255) / 256, 256, 0, stream>>>(src, dst, E, off, cursor,
                                                         dinv, csr);

    int pairs = (N + 1) / 2;
    int blocks = (pairs + 3) / 4;
    aggemm<<<blocks, 256, 0, stream>>>(xq, scales, off, csr, dinv, W, b, N, out);
}

// Round 9
// 468.185 us; speedup vs baseline: 1.7465x; 1.2215x over previous
//
#include <hip/hip_runtime.h>

#define KSL 8
#define DIN 128
#define DOUT 128

typedef __attribute__((ext_vector_type(8))) short bf16x8;
typedef __attribute__((ext_vector_type(4))) float f32x4;

// round-to-nearest-even fp32 -> bf16 bits
static __device__ __forceinline__ unsigned int f2b_bits(float f) {
    unsigned int u = __float_as_uint(f);
    return (u + 0x7fffu + ((u >> 16) & 1u)) >> 16;
}

// ---------------- quantize x -> permuted int8 + per-node scale; deg count ----
// One wave per node. Output row layout (per (node,kslice), 128B):
//   d' = g*32 + kt*8 + e   stores element d = kt*32 + g*8 + e
// so aggemm lane (rit,g) reads its 32 fragment bytes CONTIGUOUSLY (2 x b128).
// Lane v: kslice = v>>3, chunk = v&7 -> g = chunk>>1, ktb = (chunk&1)*2;
// reads fp32 d = ktb*32+g*8 .. +7 and (ktb+1)*32+g*8 .. +7; writes 16B at
// xq[node*1024 + v*16]. Per-node amax via full-wave shfl reduce.
// Degree counting (independent domain) rides along on global tid.
__global__ __launch_bounds__(256) void quant_deg(
        const float* __restrict__ x, char* __restrict__ xq,
        float* __restrict__ scales, int N,
        const int* __restrict__ dst, int E, int* __restrict__ deg) {
    long long tid = (long long)blockIdx.x * blockDim.x + threadIdx.x;
    // ---- edge degree counting (int4 loads) ----
    int e4 = E >> 2;
    if (tid < e4) {
        int4 d = ((const int4*)dst)[tid];
        atomicAdd(&deg[d.x], 1);
        atomicAdd(&deg[d.y], 1);
        atomicAdd(&deg[d.z], 1);
        atomicAdd(&deg[d.w], 1);
    }
    if (tid < (E & 3)) atomicAdd(&deg[dst[e4 * 4 + tid]], 1);

    int w = (int)(tid >> 6);          // node
    int lane = (int)(tid & 63);
    if (w >= N) return;

    int ks = lane >> 3, chunk = lane & 7;
    int g = chunk >> 1, ktb = (chunk & 1) * 2;
    const float* row = x + ((size_t)w * KSL + ks) * DIN;
    const float* pa = row + ktb * 32 + g * 8;
    const float* pb = row + (ktb + 1) * 32 + g * 8;
    float4 a0 = *(const float4*)(pa);
    float4 a1 = *(const float4*)(pa + 4);
    float4 b0 = *(const float4*)(pb);
    float4 b1 = *(const float4*)(pb + 4);

    float m = fmaxf(fmaxf(fmaxf(fabsf(a0.x), fabsf(a0.y)), fmaxf(fabsf(a0.z), fabsf(a0.w))),
                    fmaxf(fmaxf(fabsf(a1.x), fabsf(a1.y)), fmaxf(fabsf(a1.z), fabsf(a1.w))));
    m = fmaxf(m, fmaxf(fmaxf(fmaxf(fabsf(b0.x), fabsf(b0.y)), fmaxf(fabsf(b0.z), fabsf(b0.w))),
                       fmaxf(fmaxf(fabsf(b1.x), fabsf(b1.y)), fmaxf(fabsf(b1.z), fabsf(b1.w)))));
    #pragma unroll
    for (int s = 32; s > 0; s >>= 1) m = fmaxf(m, __shfl_xor(m, s));

    float inv = (m > 0.f) ? 127.f / m : 0.f;
    int q0 = __float2int_rn(a0.x * inv), q1 = __float2int_rn(a0.y * inv);
    int q2 = __float2int_rn(a0.z * inv), q3 = __float2int_rn(a0.w * inv);
    int q4 = __float2int_rn(a1.x * inv), q5 = __float2int_rn(a1.y * inv);
    int q6 = __float2int_rn(a1.z * inv), q7 = __float2int_rn(a1.w * inv);
    int r0 = __float2int_rn(b0.x * inv), r1 = __float2int_rn(b0.y * inv);
    int r2 = __float2int_rn(b0.z * inv), r3 = __float2int_rn(b0.w * inv);
    int r4 = __float2int_rn(b1.x * inv), r5 = __float2int_rn(b1.y * inv);
    int r6 = __float2int_rn(b1.z * inv), r7 = __float2int_rn(b1.w * inv);
    uint4 o;
    o.x = (q0 & 0xff) | ((q1 & 0xff) << 8) | ((q2 & 0xff) << 16) | ((unsigned)(q3 & 0xff) << 24);
    o.y = (q4 & 0xff) | ((q5 & 0xff) << 8) | ((q6 & 0xff) << 16) | ((unsigned)(q7 & 0xff) << 24);
    o.z = (r0 & 0xff) | ((r1 & 0xff) << 8) | ((r2 & 0xff) << 16) | ((unsigned)(r3 & 0xff) << 24);
    o.w = (r4 & 0xff) | ((r5 & 0xff) << 8) | ((r6 & 0xff) << 16) | ((unsigned)(r7 & 0xff) << 24);
    *(uint4*)(xq + (size_t)w * 1024 + lane * 16) = o;
    if (lane == 0) scales[w] = m * (1.f / 127.f);
}

// ---------------- CSR offsets: serial chunks + one block scan ----------------
__global__ __launch_bounds__(1024) void scan_off_fast(const int* __restrict__ deg, int N,
                                                      int* __restrict__ off,
                                                      float* __restrict__ dinv) {
    __shared__ int part[1024];
    int tid = threadIdx.x;
    int CH = (N + 1023) / 1024;
    int i0 = tid * CH;
    int s = 0;
    for (int j = 0; j < CH; j++) {
        int i = i0 + j;
        if (i < N) {
            int d = deg[i];
            dinv[i] = rsqrtf((float)(d + 1));   // +1 self-loop
            s += d;
        }
    }
    part[tid] = s;
    __syncthreads();
    for (int st = 1; st < 1024; st <<= 1) {
        int t = (tid >= st) ? part[tid - st] : 0;
        __syncthreads();
        part[tid] += t;
        __syncthreads();
    }
    int run = part[tid] - s;   // exclusive prefix
    for (int j = 0; j < CH; j++) {
        int i = i0 + j;
        if (i < N) {
            off[i] = run;
            run += deg[i];
        }
    }
    if (tid == 1023) off[N] = part[1023];
}

// ---------------- CSR fill: int4 edge loads; scale FOLDED into weight -------
__global__ __launch_bounds__(256) void fill_csr(
        const int* __restrict__ src, const int* __restrict__ dst, int E,
        const int* __restrict__ off, int* __restrict__ cursor,
        const float* __restrict__ dinv, const float* __restrict__ scales,
        int2* __restrict__ csr) {
    int i = blockIdx.x * blockDim.x + threadIdx.x;
    int e4 = E >> 2;
    if (i < e4) {
        int4 s4 = ((const int4*)src)[i];
        int4 d4 = ((const int4*)dst)[i];
        int pos;
        pos = atomicAdd(&cursor[d4.x], 1);
        csr[off[d4.x] + pos] = make_int2(s4.x, __float_as_int(dinv[s4.x] * dinv[d4.x] * scales[s4.x]));
        pos = atomicAdd(&cursor[d4.y], 1);
        csr[off[d4.y] + pos] = make_int2(s4.y, __float_as_int(dinv[s4.y] * dinv[d4.y] * scales[s4.y]));
        pos = atomicAdd(&cursor[d4.z], 1);
        csr[off[d4.z] + pos] = make_int2(s4.z, __float_as_int(dinv[s4.z] * dinv[d4.z] * scales[s4.z]));
        pos = atomicAdd(&cursor[d4.w], 1);
        csr[off[d4.w] + pos] = make_int2(s4.w, __float_as_int(dinv[s4.w] * dinv[d4.w] * scales[s4.w]));
    }
    if (i < (E & 3)) {
        int e = e4 * 4 + i;
        int s = src[e], d = dst[e];
        int pos = atomicAdd(&cursor[d], 1);
        csr[off[d] + pos] = make_int2(s, __float_as_int(dinv[s] * dinv[d] * scales[s]));
    }
}

// ---------------- fused aggregate + MFMA GEMM + bias + ReLU ----------------
// r2/r8 structure; gather = 2 x b128 per iteration (permuted int8 rows make
// each lane's 32 fragment bytes contiguous). Weight is scale-pre-folded in
// csr -> per-iteration VMEM = 2 gather + 1 csr = 192 lane-addrs (was 384).
// W staged bf16 XOR-swizzled in LDS; scalar plain stores (exact 200MB).
__global__ __launch_bounds__(256) void aggemm(
        const char* __restrict__ xq, const float* __restrict__ scales,
        const int* __restrict__ off, const int2* __restrict__ csr,
        const float* __restrict__ dinv,
        const float* __restrict__ W, const float* __restrict__ bias,
        int N, float* __restrict__ out) {
    __shared__ unsigned short Wt[128 * 128];   // [c][k] bf16, XOR-swizzled, 32 KB

    int t = threadIdx.x;
    // ---- stage W^T as bf16 with XOR swizzle on byte bits 4..6 (r2-verified) ----
    {
        int c = t & 127;
        int khalf = t >> 7;
        #pragma unroll
        for (int kc = 0; kc < 8; kc++) {
            int k0 = khalf * 64 + kc * 8;
            unsigned int u0 = f2b_bits(W[(size_t)(k0 + 0) * 128 + c]) |
                             (f2b_bits(W[(size_t)(k0 + 1) * 128 + c]) << 16);
            unsigned int u1 = f2b_bits(W[(size_t)(k0 + 2) * 128 + c]) |
                             (f2b_bits(W[(size_t)(k0 + 3) * 128 + c]) << 16);
            unsigned int u2 = f2b_bits(W[(size_t)(k0 + 4) * 128 + c]) |
                             (f2b_bits(W[(size_t)(k0 + 5) * 128 + c]) << 16);
            unsigned int u3 = f2b_bits(W[(size_t)(k0 + 6) * 128 + c]) |
                             (f2b_bits(W[(size_t)(k0 + 7) * 128 + c]) << 16);
            int byte = c * 256 + k0 * 2;
            byte ^= (c & 7) << 4;
            *(uint4*)((char*)Wt + byte) = make_uint4(u0, u1, u2, u3);
        }
    }
    __syncthreads();

    int wid = t >> 6, lane = t & 63;
    int pair = blockIdx.x * 4 + wid;
    int n0 = pair * 2;
    if (n0 >= N) return;

    int rit = lane & 15;          // row in 16-row tile
    int g   = lane >> 4;          // k-group 0..3
    int mynode = n0 + (rit >> 3);
    if (mynode >= N) mynode = n0; // odd-N guard
    int kslice = rit & 7;

    int offA = off[n0];
    int offMid = off[n0 + 1];
    int offEnd = (n0 + 2 <= N) ? off[n0 + 2] : offMid;
    int degA = offMid - offA;
    int degB = (n0 + 1 < N) ? (offEnd - offMid) : 0;
    int maxd = max(degA, degB);
    int myoff = (rit < 8) ? offA : offMid;
    int mydeg = (rit < 8) ? degA : degB;

    const size_t rofs = (size_t)kslice * 128 + g * 32;  // lane's 32B in 1KB row

    float acc[32];
    #pragma unroll
    for (int i = 0; i < 32; i++) acc[i] = 0.f;

    float selfw;
    {
        float ds = dinv[mynode];
        selfw = ds * ds * scales[mynode];
    }

    for (int j = -1; j < maxd; j++) {
        int s;
        float wgt;
        if (j < 0) {
            s = mynode;
            wgt = selfw;
        } else if (j < mydeg) {
            int2 cc = csr[myoff + j];
            s = cc.x;
            wgt = __int_as_float(cc.y);
        } else {
            s = mynode;
            wgt = 0.f;
        }
        const uint4* rb = (const uint4*)(xq + (size_t)s * 1024 + rofs);
        uint4 q0 = rb[0];           // kt0,kt1 (bytes d' = kt*8+e)
        uint4 q1 = rb[1];           // kt2,kt3
        #define UNPK(wrd, base)                                              \
            acc[(base) + 0] += (float)(signed char)((wrd)      )  * wgt;     \
            acc[(base) + 1] += (float)(signed char)((wrd) >>  8) * wgt;      \
            acc[(base) + 2] += (float)(signed char)((wrd) >> 16) * wgt;      \
            acc[(base) + 3] += (float)(signed char)((wrd) >> 24) * wgt;
        UNPK(q0.x, 0)  UNPK(q0.y, 4)  UNPK(q0.z, 8)  UNPK(q0.w, 12)
        UNPK(q1.x, 16) UNPK(q1.y, 20) UNPK(q1.z, 24) UNPK(q1.w, 28)
        #undef UNPK
    }

    // pack accumulators -> A fragments (bf16); acc[kt*8+e] = d kt*32+g*8+e
    bf16x8 afrag[4];
    #pragma unroll
    for (int kt = 0; kt < 4; kt++) {
        #pragma unroll
        for (int e = 0; e < 8; e++)
            afrag[kt][e] = (short)f2b_bits(acc[kt * 8 + e]);
    }

    // GEMM: 8 column tiles of 16, K = 128 in 4 MFMAs each; B-frags from LDS
    long long r0 = (long long)n0 * 8;
    #pragma unroll
    for (int ct = 0; ct < 8; ct++) {
        int c = ct * 16 + rit;     // output column (C/D: col = lane&15)
        f32x4 acct = {0.f, 0.f, 0.f, 0.f};
        #pragma unroll
        for (int kt = 0; kt < 4; kt++) {
            int byte = c * 256 + kt * 64 + g * 16;
            byte ^= (c & 7) << 4;
            bf16x8 bfrag = *(const bf16x8*)((const char*)Wt + byte);
            acct = __builtin_amdgcn_mfma_f32_16x16x32_bf16(afrag[kt], bfrag, acct, 0, 0, 0);
        }
        float bv = bias[c];
        #pragma unroll
        for (int r = 0; r < 4; r++) {
            long long row = r0 + g * 4 + r;   // C/D: row = (lane>>4)*4 + reg
            out[row * 128 + c] = fmaxf(acct[r] + bv, 0.f);
        }
    }
}

// ---------------- launch ----------------
extern "C" void kernel_launch(void* const* d_in, const int* in_sizes, int n_in,
                              void* d_out, int out_size, void* d_ws, size_t ws_size,
                              hipStream_t stream) {
    const float* x  = (const float*)d_in[0];
    const int*   ei = (const int*)d_in[1];
    const float* W  = (const float*)d_in[2];
    const float* b  = (const float*)d_in[3];
    float* out = (float*)d_out;

    int N = in_sizes[0] / (KSL * DIN);
    int E = in_sizes[1] / 2;
    const int* src = ei;
    const int* dst = ei + E;

    char* ws = (char*)d_ws;
    size_t o = 0;
    auto alloc = [&](size_t bytes) -> void* {
        o = (o + 255) & ~(size_t)255;
        void* p = ws + o;
        o += bytes;
        return p;
    };
    int*   deg    = (int*)alloc((size_t)N * 4);
    int*   cursor = (int*)alloc((size_t)N * 4);     // adjacent to deg: one memset
    int*   off    = (int*)alloc((size_t)(N + 1) * 4);
    float* dinv   = (float*)alloc((size_t)N * 4);
    float* scales = (float*)alloc((size_t)N * 4);
    int2*  csr    = (int2*)alloc((size_t)(E + 1) * 8);
    char*  xq     = (char*)alloc((size_t)N * KSL * DIN);

    // one memset covers deg + alignment gap + cursor
    size_t z_bytes = (size_t)((char*)cursor - (char*)deg) + (size_t)N * 4;
    hipMemsetAsync(deg, 0, z_bytes, stream);

    long long qthreads = (long long)N * 64;
    int qblocks = (int)((qthreads + 255) / 256);
    quant_deg<<<qblocks, 256, 0, stream>>>(x, xq, scales, N, dst, E, deg);
    scan_off_fast<<<1, 1024, 0, stream>>>(deg, N, off, dinv);
    fill_csr<<<((E >> 2) + 255) / 256, 256, 0, stream>>>(src, dst, E, off, cursor,
                                                         dinv, scales, csr);

    int pairs = (N + 1) / 2;
    int blocks = (pairs + 3) / 4;
    aggemm<<<blocks, 256, 0, stream>>>(xq, scales, off, csr, dinv, W, b, N, out);
}